// Round 10
// baseline (303.799 us; speedup 1.0000x reference)
//
#include <hip/hip_runtime.h>

// GraphConvolution (Chebyshev K=5) on MI355X — round 10.
// vs round 9:
//  (a) SpMM: padded-CSR. Rows padded to a strict multiple of 8 edges
//      ((deg+8)&~7; pad word = 0 -> col 0, val 0 -> exact-zero fma). Lane
//      (r,q) broadcast-loads all 8 cv words of its row's strip with a
//      branch-free min(t,plim) clamp -> inner loop has NO shfl, NO exec-mask
//      churn, 16 cv + 16 gather loads all independent. (Round 9's chain
//      cv->shfl x8->gather throttled MLP; spmm stuck ~45 us at only 50 MB.)
//  (b) transform_x: coalesced (wave reads 1 KB contiguous; b,b^1 adjacent
//      waves so 32-B half-line writes merge).
//  (c) gemm: pair = blockIdx&7 -> block reading slice p runs on XCD p
//      (x3b slice p was read-allocated there by spmm pass 4).
// Slice placement unchanged: [8][M][32] bf16, slice = blockIdx&7 -> XCD.

constexpr int M   = 49152;
constexpr int B   = 16;
constexpr int FIN = 16;
constexpr int F1  = 32;
constexpr int K   = 5;
constexpr int XBS = M * FIN;                 // per-b stride in x[B,M,FIN]
constexpr size_t SLICEB   = (size_t)M * 64;  // bytes per feature slice
constexpr size_t BUFBYTES = (size_t)M * 512; // bytes per xs_k buffer (8 slices)
constexpr int NBLK_M = M / 256;              // 192 blocks over rows
constexpr int NHB = 64 * NBLK_M;             // 12288 bin-major hist entries

typedef short s16x8 __attribute__((ext_vector_type(8)));
typedef float f32x4 __attribute__((ext_vector_type(4)));
typedef unsigned int u32;
typedef unsigned long long u64;

#define DEVFN __device__ __forceinline__

DEVFN float lo2f(u32 d) {
  union { u32 u; float f; } v; v.u = d << 16; return v.f;
}
DEVFN float hi2f(u32 d) {
  union { u32 u; float f; } v; v.u = d & 0xffff0000u; return v.f;
}
DEVFN unsigned short f2bf(float f) {   // round-to-nearest-even
  union { float f; u32 u; } v;
  v.f = f;
  u32 r = (v.u + 0x7FFFu + ((v.u >> 16) & 1u)) >> 16;
  return (unsigned short)r;
}

// ---------------- x -> bf16 slice-major [8][M][32], coalesced ----------------
// blockIdx = (mchunk, bquad); wave -> b = bquad*4+wave; lane -> (m_off, f).
// Read: 64 lanes x 16 B = 1 KB contiguous. Write: 16 m x 32 B (half-lines;
// partner half written by wave b^1 of the same block).

__global__ __launch_bounds__(256) void transform_x(const float* __restrict__ x,
                                                   char* __restrict__ x0b) {
  int lane = threadIdx.x & 63, wave = threadIdx.x >> 6;
  int mchunk = blockIdx.x >> 2, bquad = blockIdx.x & 3;
  int b = bquad * 4 + wave;
  int m = mchunk * 16 + (lane >> 2);
  int f = (lane & 3) * 4;
  float4 v = *(const float4*)(x + (size_t)b * XBS + (size_t)m * FIN + f);
  ushort4 r = make_ushort4(f2bf(v.x), f2bf(v.y), f2bf(v.z), f2bf(v.w));
  *(ushort4*)(x0b + (size_t)(b >> 1) * SLICEB + (size_t)m * 64 +
              (size_t)(b & 1) * 32 + (size_t)(lane & 3) * 8) = r;
}

// ---------------- CSR build ----------------

__global__ __launch_bounds__(256) void hist_kernel(const int* __restrict__ rows,
                                                   int* __restrict__ counts, int nnz) {
  int i = blockIdx.x * 256 + threadIdx.x;
  if (i < nnz) atomicAdd(&counts[rows[i]], 1);
}

// padded counts: strict next multiple of 8 (>= deg+1, so the last word of
// every row is ALWAYS a pad word -> min(t,plim) clamp is exact)
__global__ __launch_bounds__(256) void pad_counts(const int* __restrict__ counts,
                                                  int* __restrict__ c8) {
  int m = blockIdx.x * 256 + threadIdx.x;
  c8[m] = (counts[m] + 8) & ~7;
}

DEVFN int wave_incl_scan(int v, int lane) {
#pragma unroll
  for (int off = 1; off < 64; off <<= 1) {
    int t = __shfl_up(v, off);
    if (lane >= off) v += t;
  }
  return v;
}

// generic: per-block inclusive scan of src -> dst[i+1], block total -> partials
__global__ __launch_bounds__(1024) void scan_blocks(const int* __restrict__ src,
                                                    int* __restrict__ dst,
                                                    int* __restrict__ partials) {
  __shared__ int wsum[16];
  int tid = threadIdx.x, lane = tid & 63, w = tid >> 6;
  int i = blockIdx.x * 1024 + tid;
  int s = wave_incl_scan(src[i], lane);
  if (lane == 63) wsum[w] = s;
  __syncthreads();
  if (tid < 16) {
    int t = wsum[tid];
#pragma unroll
    for (int off = 1; off < 16; off <<= 1) {
      int u = __shfl_up(t, off);
      if (tid >= off) t += u;
    }
    wsum[tid] = t;
  }
  __syncthreads();
  int base = (w > 0) ? wsum[w - 1] : 0;
  s += base;
  dst[i + 1] = s;
  if (tid == 1023) partials[blockIdx.x] = s;
}

__global__ void scan_partials_kernel(int* __restrict__ partials,
                                     int* __restrict__ dst, int nblk) {
  int lane = threadIdx.x;  // 64 threads
  int v = (lane < nblk) ? partials[lane] : 0;
  v = wave_incl_scan(v, lane);
  if (lane < nblk) partials[lane] = v;
  if (lane == 0) dst[0] = 0;
}

__global__ __launch_bounds__(1024) void scan_add_kernel(int* __restrict__ dst,
                                                        const int* __restrict__ partials) {
  if (blockIdx.x == 0) return;
  int i = blockIdx.x * 1024 + threadIdx.x;
  dst[i + 1] += partials[blockIdx.x - 1];
}

// cv entry: col (high 16) | val-bf16 (low 16); scattered into the PADDED
// layout (bases from row_ptr8; pad gaps stay 0 from the memset)
__global__ __launch_bounds__(256) void scatter_kernel(const int* __restrict__ rows,
                                                      const int* __restrict__ cols,
                                                      const float* __restrict__ vals,
                                                      const int* __restrict__ row_ptr8,
                                                      int* __restrict__ fill,
                                                      u32* __restrict__ cvp, int nnz) {
  int i = blockIdx.x * 256 + threadIdx.x;
  if (i < nnz) {
    int r = rows[i];
    int pos = row_ptr8[r] + atomicAdd(&fill[r], 1);
    cvp[pos] = ((u32)cols[i] << 16) | (u32)f2bf(vals[i]);
  }
}

// ---------------- degree counting sort (contention-free) ----------------

__global__ __launch_bounds__(256) void deg_hist_blk(const int* __restrict__ counts,
                                                    int* __restrict__ blkhist) {
  __shared__ int lh[64];
  int tid = threadIdx.x;
  if (tid < 64) lh[tid] = 0;
  __syncthreads();
  int m = blockIdx.x * 256 + tid;
  atomicAdd(&lh[min(counts[m], 63)], 1);
  __syncthreads();
  if (tid < 64) blkhist[tid * NBLK_M + blockIdx.x] = lh[tid];
}

__global__ __launch_bounds__(256) void perm_scatter_blk(const int* __restrict__ counts,
                                                        const int* __restrict__ sc,
                                                        int* __restrict__ perm) {
  __shared__ int lh[64];
  __shared__ int lbase[64];
  int tid = threadIdx.x, blk = blockIdx.x;
  if (tid < 64) lh[tid] = 0;
  __syncthreads();
  int m = blk * 256 + tid;
  int d = min(counts[m], 63);
  int lr = atomicAdd(&lh[d], 1);          // LDS-local rank
  __syncthreads();
  if (tid < 64) lbase[tid] = sc[tid * NBLK_M + blk];
  __syncthreads();
  perm[lbase[d] + lr] = m;
}

// ---------------- SpMM: XCD-sliced, padded-CSR, branch-free ----------------
// slice s = blockIdx&7 (-> XCD). Wave = 16 rows (two degree-adjacent groups
// of 8) x 8 q-chunks; lane (r,q) owns features q*4..+3 of its rows and
// broadcast-loads all 8 cv words of each strip with min(t,plim) clamp
// (plim always points at a pad word = 0 -> exact-zero contribution).
// Inner loop: 16 cv loads + 16 gathers, all independent; no shfl, no masks.

template <bool SUB>
__global__ __launch_bounds__(256) void spmm_pad(const char* __restrict__ xsrc,
                                                const char* __restrict__ ssrc,
                                                char* __restrict__ y,
                                                const int* __restrict__ row_ptr8,
                                                const int* __restrict__ perm,
                                                const u32* __restrict__ cvp) {
  int s  = blockIdx.x & 7;
  int g4 = blockIdx.x >> 3;
  int lane = threadIdx.x & 63, wave = threadIdx.x >> 6;
  int r = lane >> 3, q = lane & 7;
  int grp = g4 * 4 + wave;                 // 16-row group index
  const char* sbase = xsrc + (size_t)s * SLICEB;
  size_t qb = (size_t)q * 8;

  int ridA = perm[grp * 16 + r];
  int ridB = perm[grp * 16 + 8 + r];
  int baseA = row_ptr8[ridA], baseB = row_ptr8[ridB];
  int plimA = row_ptr8[ridA + 1] - baseA - 1;   // last word: always pad
  int plimB = row_ptr8[ridB + 1] - baseB - 1;

  int wns = (max(plimA, plimB) + 1) >> 3;       // strips (wave max below)
  wns = max(wns, __shfl_xor(wns, 8));
  wns = max(wns, __shfl_xor(wns, 16));
  wns = max(wns, __shfl_xor(wns, 32));

  u64 svA = 0, svB = 0;
  if (SUB) {
    svA = __builtin_nontemporal_load(
        (const u64*)(ssrc + (size_t)s * SLICEB + (size_t)ridA * 64 + qb));
    svB = __builtin_nontemporal_load(
        (const u64*)(ssrc + (size_t)s * SLICEB + (size_t)ridB * 64 + qb));
  }

  float aA0 = 0.f, aA1 = 0.f, aA2 = 0.f, aA3 = 0.f;
  float aB0 = 0.f, aB1 = 0.f, aB2 = 0.f, aB3 = 0.f;
  int nedge = wns * 8;
  for (int t0 = 0; t0 < nedge; t0 += 8) {
    u32 cA[8], cB[8];
    u64 dA[8], dB[8];
#pragma unroll
    for (int t = 0; t < 8; ++t) cA[t] = cvp[baseA + min(t0 + t, plimA)];
#pragma unroll
    for (int t = 0; t < 8; ++t) cB[t] = cvp[baseB + min(t0 + t, plimB)];
#pragma unroll
    for (int t = 0; t < 8; ++t)
      dA[t] = *(const u64*)(sbase + (size_t)(cA[t] >> 16) * 64 + qb);
#pragma unroll
    for (int t = 0; t < 8; ++t)
      dB[t] = *(const u64*)(sbase + (size_t)(cB[t] >> 16) * 64 + qb);
#pragma unroll
    for (int t = 0; t < 8; ++t) {
      float v = lo2f(cA[t]);
      u32 dl = (u32)dA[t], dh = (u32)(dA[t] >> 32);
      aA0 = fmaf(v, lo2f(dl), aA0); aA1 = fmaf(v, hi2f(dl), aA1);
      aA2 = fmaf(v, lo2f(dh), aA2); aA3 = fmaf(v, hi2f(dh), aA3);
    }
#pragma unroll
    for (int t = 0; t < 8; ++t) {
      float v = lo2f(cB[t]);
      u32 dl = (u32)dB[t], dh = (u32)(dB[t] >> 32);
      aB0 = fmaf(v, lo2f(dl), aB0); aB1 = fmaf(v, hi2f(dl), aB1);
      aB2 = fmaf(v, lo2f(dh), aB2); aB3 = fmaf(v, hi2f(dh), aB3);
    }
  }

  if (SUB) {
    u32 sl = (u32)svA, sh = (u32)(svA >> 32);
    aA0 = fmaf(2.f, aA0, -lo2f(sl)); aA1 = fmaf(2.f, aA1, -hi2f(sl));
    aA2 = fmaf(2.f, aA2, -lo2f(sh)); aA3 = fmaf(2.f, aA3, -hi2f(sh));
    sl = (u32)svB; sh = (u32)(svB >> 32);
    aB0 = fmaf(2.f, aB0, -lo2f(sl)); aB1 = fmaf(2.f, aB1, -hi2f(sl));
    aB2 = fmaf(2.f, aB2, -lo2f(sh)); aB3 = fmaf(2.f, aB3, -hi2f(sh));
  }
  u64 rvA = ((u64)(((u32)f2bf(aA3) << 16) | (u32)f2bf(aA2)) << 32) |
            (u64)(((u32)f2bf(aA1) << 16) | (u32)f2bf(aA0));
  u64 rvB = ((u64)(((u32)f2bf(aB3) << 16) | (u32)f2bf(aB2)) << 32) |
            (u64)(((u32)f2bf(aB1) << 16) | (u32)f2bf(aB0));
  __builtin_nontemporal_store(
      rvA, (u64*)(y + (size_t)s * SLICEB + (size_t)ridA * 64 + qb));
  __builtin_nontemporal_store(
      rvB, (u64*)(y + (size_t)s * SLICEB + (size_t)ridB * 64 + qb));
}

// ---------------- Final contraction via MFMA ----------------
// out[(b*M+m)*32+o] = sum_{k,f} xs_k[m][b*16+f] * kern[(f*5+k)*32+o] + bias[o]
// kk = c*32 + g*8 + j <-> k = 2c+(g>>1), f = (g&1)*8+j; 3 chunks of K=32.
// pair = blockIdx&7 -> the block reading slice p runs on XCD p.

__global__ __launch_bounds__(256) void cheb_gemm_mfma(const char* __restrict__ xs0,
                                                      const float* __restrict__ kern,
                                                      const float* __restrict__ bias,
                                                      float* __restrict__ out) {
  __shared__ unsigned short bl[3][4][32][8];  // [c][g][o][j] = B_kk,o  (6 KB)
  __shared__ float bsl[32];
  int tid = threadIdx.x;
  for (int idx = tid; idx < 3 * 4 * 32 * 8; idx += 256) {
    int j = idx & 7, o = (idx >> 3) & 31, g = (idx >> 8) & 3, c = idx >> 10;
    int k = 2 * c + (g >> 1), f = (g & 1) * 8 + j;
    bl[c][g][o][j] = (k < K) ? f2bf(kern[(f * K + k) * F1 + o]) : (unsigned short)0;
  }
  if (tid < 32) bsl[tid] = bias[tid];
  __syncthreads();

  int lane = tid & 63, wave = tid >> 6;
  int pair = blockIdx.x & 7;
  int bb = wave & 1;
  int mtg = (blockIdx.x >> 3) * 2 + (wave >> 1);   // 0..383
  int b = pair * 2 + bb;
  int mt0 = mtg * 8;                               // first 16-row m-tile of 8

  int row = lane & 15, g = lane >> 4;
  int col = lane & 15;

  s16x8 bf[3][2];
#pragma unroll
  for (int c = 0; c < 3; ++c) {
#pragma unroll
    for (int ot = 0; ot < 2; ++ot)
      bf[c][ot] = *(const s16x8*)(&bl[c][g][col + 16 * ot][0]);
  }
  float bias0 = bsl[col], bias1 = bsl[col + 16];

  size_t lanebyte = (size_t)pair * SLICEB + (size_t)row * 64 +
                    (size_t)bb * 32 + (size_t)(g & 1) * 16;
  int khalf = g >> 1;
  const char* p0 = xs0 + (size_t)(0 + khalf) * BUFBYTES + lanebyte;
  const char* p1 = xs0 + (size_t)(2 + khalf) * BUFBYTES + lanebyte;
  const char* p2 = xs0 + (size_t)(4 + khalf) * BUFBYTES + lanebyte;  // valid g<2

  size_t obase0 = ((size_t)b * M + (size_t)mt0 * 16) * F1;

#pragma unroll 2
  for (int t = 0; t < 8; ++t) {
    size_t moff = (size_t)(mt0 + t) * (16 * 64);
    s16x8 a0 = *(const s16x8*)(p0 + moff);
    s16x8 a1 = *(const s16x8*)(p1 + moff);
    s16x8 a2 = (g < 2) ? *(const s16x8*)(p2 + moff) : (s16x8)0;

    f32x4 acc0 = {0.f, 0.f, 0.f, 0.f};
    f32x4 acc1 = {0.f, 0.f, 0.f, 0.f};
    acc0 = __builtin_amdgcn_mfma_f32_16x16x32_bf16(a0, bf[0][0], acc0, 0, 0, 0);
    acc1 = __builtin_amdgcn_mfma_f32_16x16x32_bf16(a0, bf[0][1], acc1, 0, 0, 0);
    acc0 = __builtin_amdgcn_mfma_f32_16x16x32_bf16(a1, bf[1][0], acc0, 0, 0, 0);
    acc1 = __builtin_amdgcn_mfma_f32_16x16x32_bf16(a1, bf[1][1], acc1, 0, 0, 0);
    acc0 = __builtin_amdgcn_mfma_f32_16x16x32_bf16(a2, bf[2][0], acc0, 0, 0, 0);
    acc1 = __builtin_amdgcn_mfma_f32_16x16x32_bf16(a2, bf[2][1], acc1, 0, 0, 0);

    float* ob = out + obase0 + (size_t)t * (16 * F1);
#pragma unroll
    for (int j = 0; j < 4; ++j) {
      int r = g * 4 + j;
      ob[r * F1 + col]      = acc0[j] + bias0;
      ob[r * F1 + col + 16] = acc1[j] + bias1;
    }
  }
}

// ---------------- launch ----------------

extern "C" void kernel_launch(void* const* d_in, const int* in_sizes, int n_in,
                              void* d_out, int out_size, void* d_ws, size_t ws_size,
                              hipStream_t stream) {
  const float* x    = (const float*)d_in[0];
  const int*   rows = (const int*)d_in[1];
  const int*   cols = (const int*)d_in[2];
  const float* vals = (const float*)d_in[3];
  const float* kern = (const float*)d_in[4];
  const float* bias = (const float*)d_in[5];
  float* out = (float*)d_out;
  int nnz = in_sizes[1];
  int padWords = nnz + 8 * M + 256;               // cvp8 upper bound

  // workspace layout (~130 MiB); xs buffers contiguous, each slice-major.
  char* x0b = (char*)d_ws;
  char* x1b = x0b + BUFBYTES;
  char* x2b = x1b + BUFBYTES;
  char* x3b = x2b + BUFBYTES;
  char* x4b = x3b + BUFBYTES;
  int* row_ptr8 = (int*)(x4b + BUFBYTES);         // M+1 (padded to M+256)
  int* counts   = row_ptr8 + (M + 256);           // M  (raw degree)
  int* fill     = counts + M;                     // M  (scatter cursor)
  int* c8       = fill + M;                       // M  (padded counts)
  int* partials = c8 + M;                         // 64 (padded to 256)
  int* blkhist  = partials + 256;                 // 12288 bin-major hist
  int* sc       = blkhist + NHB;                  // 12288+1 (padded to +256)
  int* perm     = sc + NHB + 256;                 // M
  u32* cvp8     = (u32*)(perm + M);               // padded cv words

  int nblk1024 = M / 1024;                        // 48
  int nblkH    = NHB / 1024;                      // 12
  int nblkNnz  = (nnz + 255) / 256;

  transform_x<<<(M / 16) * 4, 256, 0, stream>>>(x, x0b);

  hipMemsetAsync(counts, 0, (size_t)2 * M * 4, stream);   // counts + fill
  hipMemsetAsync(cvp8, 0, (size_t)padWords * 4, stream);  // pad words = 0
  hist_kernel<<<nblkNnz, 256, 0, stream>>>(rows, counts, nnz);
  pad_counts<<<NBLK_M, 256, 0, stream>>>(counts, c8);
  // row_ptr8 = exclusive scan of padded counts
  scan_blocks<<<nblk1024, 1024, 0, stream>>>(c8, row_ptr8, partials);
  scan_partials_kernel<<<1, 64, 0, stream>>>(partials, row_ptr8, nblk1024);
  scan_add_kernel<<<nblk1024, 1024, 0, stream>>>(row_ptr8, partials);
  // degree counting sort -> perm
  deg_hist_blk<<<NBLK_M, 256, 0, stream>>>(counts, blkhist);
  scan_blocks<<<nblkH, 1024, 0, stream>>>(blkhist, sc, partials);
  scan_partials_kernel<<<1, 64, 0, stream>>>(partials, sc, nblkH);
  scan_add_kernel<<<nblkH, 1024, 0, stream>>>(sc, partials);
  perm_scatter_blk<<<NBLK_M, 256, 0, stream>>>(counts, sc, perm);
  // CSR scatter into padded layout
  scatter_kernel<<<nblkNnz, 256, 0, stream>>>(rows, cols, vals, row_ptr8, fill, cvp8, nnz);

  // Chebyshev recurrence (bf16, slice-major, fp32 accumulate)
  int spmmGrid = 8 * (M / 64);                    // 6144 blocks
  spmm_pad<false><<<spmmGrid, 256, 0, stream>>>(x0b, nullptr, x1b, row_ptr8, perm, cvp8);
  spmm_pad<true ><<<spmmGrid, 256, 0, stream>>>(x1b, x0b, x2b, row_ptr8, perm, cvp8);
  spmm_pad<true ><<<spmmGrid, 256, 0, stream>>>(x2b, x1b, x3b, row_ptr8, perm, cvp8);
  spmm_pad<true ><<<spmmGrid, 256, 0, stream>>>(x3b, x2b, x4b, row_ptr8, perm, cvp8);

  // final contraction + bias via MFMA: 1536 blocks x 4 waves
  cheb_gemm_mfma<<<1536, 256, 0, stream>>>(x0b, kern, bias, out);

  (void)n_in; (void)out_size; (void)ws_size; (void)in_sizes;
}

// Round 11
// 282.923 us; speedup vs baseline: 1.0738x; 1.0738x over previous
//
#include <hip/hip_runtime.h>

// GraphConvolution (Chebyshev K=5) on MI355X — round 11.
// vs round 10:
//  (a) SpMM gathers widened 8 B -> 16 B per lane (lane = (row r 0..15,
//      chunk q2 0..3); 4 lanes/edge). Divergent-gather cost scales with
//      ADDRESS COUNT (~1 addr/cy/CU): 25.2M -> 12.6M addrs/pass, predicted
//      ~2x. Rounds 2-10's six spmm shapes all hit 45-55 us because 8-B lanes
//      pinned the address count (or, unsliced, the fabric) at the same ~50 us.
//  (b) gemm: B-fragments reindexed to adjacent output columns (o = 2c, 2c+1)
//      -> float2 stores (half the store instructions).
//  (c) pad_counts folded into deg_hist_blk.
// Unchanged: [8][M][32] bf16 slice layout (slice = blockIdx&7 -> XCD,
// gathers L2-resident), padded-CSR branch-free strips, degree sort,
// contention-free counting sort, MFMA gemm.

constexpr int M   = 49152;
constexpr int B   = 16;
constexpr int FIN = 16;
constexpr int F1  = 32;
constexpr int K   = 5;
constexpr int XBS = M * FIN;                 // per-b stride in x[B,M,FIN]
constexpr size_t SLICEB   = (size_t)M * 64;  // bytes per feature slice
constexpr size_t BUFBYTES = (size_t)M * 512; // bytes per xs_k buffer (8 slices)
constexpr int NBLK_M = M / 256;              // 192 blocks over rows
constexpr int NHB = 64 * NBLK_M;             // 12288 bin-major hist entries

typedef short s16x8 __attribute__((ext_vector_type(8)));
typedef float f32x4 __attribute__((ext_vector_type(4)));
typedef unsigned int u32;
typedef unsigned long long u64;
typedef u32 u32x4 __attribute__((ext_vector_type(4)));

#define DEVFN __device__ __forceinline__

DEVFN float lo2f(u32 d) {
  union { u32 u; float f; } v; v.u = d << 16; return v.f;
}
DEVFN float hi2f(u32 d) {
  union { u32 u; float f; } v; v.u = d & 0xffff0000u; return v.f;
}
DEVFN unsigned short f2bf(float f) {   // round-to-nearest-even
  union { float f; u32 u; } v;
  v.f = f;
  u32 r = (v.u + 0x7FFFu + ((v.u >> 16) & 1u)) >> 16;
  return (unsigned short)r;
}

// ---------------- x -> bf16 slice-major [8][M][32], coalesced ----------------

__global__ __launch_bounds__(256) void transform_x(const float* __restrict__ x,
                                                   char* __restrict__ x0b) {
  int lane = threadIdx.x & 63, wave = threadIdx.x >> 6;
  int mchunk = blockIdx.x >> 2, bquad = blockIdx.x & 3;
  int b = bquad * 4 + wave;
  int m = mchunk * 16 + (lane >> 2);
  int f = (lane & 3) * 4;
  float4 v = *(const float4*)(x + (size_t)b * XBS + (size_t)m * FIN + f);
  ushort4 r = make_ushort4(f2bf(v.x), f2bf(v.y), f2bf(v.z), f2bf(v.w));
  *(ushort4*)(x0b + (size_t)(b >> 1) * SLICEB + (size_t)m * 64 +
              (size_t)(b & 1) * 32 + (size_t)(lane & 3) * 8) = r;
}

// ---------------- CSR build ----------------

__global__ __launch_bounds__(256) void hist_kernel(const int* __restrict__ rows,
                                                   int* __restrict__ counts, int nnz) {
  int i = blockIdx.x * 256 + threadIdx.x;
  if (i < nnz) atomicAdd(&counts[rows[i]], 1);
}

DEVFN int wave_incl_scan(int v, int lane) {
#pragma unroll
  for (int off = 1; off < 64; off <<= 1) {
    int t = __shfl_up(v, off);
    if (lane >= off) v += t;
  }
  return v;
}

// generic: per-block inclusive scan of src -> dst[i+1], block total -> partials
__global__ __launch_bounds__(1024) void scan_blocks(const int* __restrict__ src,
                                                    int* __restrict__ dst,
                                                    int* __restrict__ partials) {
  __shared__ int wsum[16];
  int tid = threadIdx.x, lane = tid & 63, w = tid >> 6;
  int i = blockIdx.x * 1024 + tid;
  int s = wave_incl_scan(src[i], lane);
  if (lane == 63) wsum[w] = s;
  __syncthreads();
  if (tid < 16) {
    int t = wsum[tid];
#pragma unroll
    for (int off = 1; off < 16; off <<= 1) {
      int u = __shfl_up(t, off);
      if (tid >= off) t += u;
    }
    wsum[tid] = t;
  }
  __syncthreads();
  int base = (w > 0) ? wsum[w - 1] : 0;
  s += base;
  dst[i + 1] = s;
  if (tid == 1023) partials[blockIdx.x] = s;
}

__global__ void scan_partials_kernel(int* __restrict__ partials,
                                     int* __restrict__ dst, int nblk) {
  int lane = threadIdx.x;  // 64 threads
  int v = (lane < nblk) ? partials[lane] : 0;
  v = wave_incl_scan(v, lane);
  if (lane < nblk) partials[lane] = v;
  if (lane == 0) dst[0] = 0;
}

__global__ __launch_bounds__(1024) void scan_add_kernel(int* __restrict__ dst,
                                                        const int* __restrict__ partials) {
  if (blockIdx.x == 0) return;
  int i = blockIdx.x * 1024 + threadIdx.x;
  dst[i + 1] += partials[blockIdx.x - 1];
}

// cv entry: col (high 16) | val-bf16 (low 16); scattered into the PADDED
// layout (bases from row_ptr8; pad gaps stay 0 from the memset)
__global__ __launch_bounds__(256) void scatter_kernel(const int* __restrict__ rows,
                                                      const int* __restrict__ cols,
                                                      const float* __restrict__ vals,
                                                      const int* __restrict__ row_ptr8,
                                                      int* __restrict__ fill,
                                                      u32* __restrict__ cvp, int nnz) {
  int i = blockIdx.x * 256 + threadIdx.x;
  if (i < nnz) {
    int r = rows[i];
    int pos = row_ptr8[r] + atomicAdd(&fill[r], 1);
    cvp[pos] = ((u32)cols[i] << 16) | (u32)f2bf(vals[i]);
  }
}

// ---------------- degree counting sort (contention-free) ----------------
// also emits padded counts c8 = strict next multiple of 8 (>= deg+1)

__global__ __launch_bounds__(256) void deg_hist_blk(const int* __restrict__ counts,
                                                    int* __restrict__ c8,
                                                    int* __restrict__ blkhist) {
  __shared__ int lh[64];
  int tid = threadIdx.x;
  if (tid < 64) lh[tid] = 0;
  __syncthreads();
  int m = blockIdx.x * 256 + tid;
  int d = counts[m];
  c8[m] = (d + 8) & ~7;
  atomicAdd(&lh[min(d, 63)], 1);
  __syncthreads();
  if (tid < 64) blkhist[tid * NBLK_M + blockIdx.x] = lh[tid];
}

__global__ __launch_bounds__(256) void perm_scatter_blk(const int* __restrict__ counts,
                                                        const int* __restrict__ sc,
                                                        int* __restrict__ perm) {
  __shared__ int lh[64];
  __shared__ int lbase[64];
  int tid = threadIdx.x, blk = blockIdx.x;
  if (tid < 64) lh[tid] = 0;
  __syncthreads();
  int m = blk * 256 + tid;
  int d = min(counts[m], 63);
  int lr = atomicAdd(&lh[d], 1);          // LDS-local rank
  __syncthreads();
  if (tid < 64) lbase[tid] = sc[tid * NBLK_M + blk];
  __syncthreads();
  perm[lbase[d] + lr] = m;
}

// ---------------- SpMM: XCD-sliced, padded-CSR, 16-B gathers ----------------
// slice s = blockIdx&7 (-> XCD). Wave = 16 rows x 4 chunks; lane (r,q2) owns
// features q2*8..q2*8+7 of row perm[grp*16+r] and accumulates locally.
// Strip = 8 edges: 8 cv loads (quad-broadcast, min(t,plim) clamp; plim always
// a pad word = 0 -> exact zero) + 8 independent 16-B gathers + 64 fma.
// No shfl, no exec-mask churn in the loop.

template <bool SUB>
__global__ __launch_bounds__(256) void spmm_pad16(const char* __restrict__ xsrc,
                                                  const char* __restrict__ ssrc,
                                                  char* __restrict__ y,
                                                  const int* __restrict__ row_ptr8,
                                                  const int* __restrict__ perm,
                                                  const u32* __restrict__ cvp) {
  int s  = blockIdx.x & 7;
  int g4 = blockIdx.x >> 3;
  int lane = threadIdx.x & 63, wave = threadIdx.x >> 6;
  int r = lane >> 2, q2 = lane & 3;
  int grp = g4 * 4 + wave;                 // 16-row group index
  const char* sbase = xsrc + (size_t)s * SLICEB;
  size_t qb = (size_t)q2 * 16;

  int rid  = perm[grp * 16 + r];
  int base = row_ptr8[rid];
  int plim = row_ptr8[rid + 1] - base - 1;   // last word: always pad (=0)

  int wns = (plim + 1) >> 3;                 // strips; wave max
  wns = max(wns, __shfl_xor(wns, 4));
  wns = max(wns, __shfl_xor(wns, 8));
  wns = max(wns, __shfl_xor(wns, 16));
  wns = max(wns, __shfl_xor(wns, 32));

  u64 sv0 = 0, sv1 = 0;
  if (SUB) {
    const char* sp = ssrc + (size_t)s * SLICEB + (size_t)rid * 64 + qb;
    sv0 = __builtin_nontemporal_load((const u64*)sp);
    sv1 = __builtin_nontemporal_load((const u64*)(sp + 8));
  }

  float a0 = 0.f, a1 = 0.f, a2 = 0.f, a3 = 0.f;
  float a4 = 0.f, a5 = 0.f, a6 = 0.f, a7 = 0.f;
  int nedge = wns * 8;
  for (int t0 = 0; t0 < nedge; t0 += 8) {
    u32 cA[8];
    u32x4 dA[8];
#pragma unroll
    for (int t = 0; t < 8; ++t) cA[t] = cvp[base + min(t0 + t, plim)];
#pragma unroll
    for (int t = 0; t < 8; ++t)
      dA[t] = *(const u32x4*)(sbase + (size_t)(cA[t] >> 16) * 64 + qb);
#pragma unroll
    for (int t = 0; t < 8; ++t) {
      float v = lo2f(cA[t]);
      a0 = fmaf(v, lo2f(dA[t].x), a0); a1 = fmaf(v, hi2f(dA[t].x), a1);
      a2 = fmaf(v, lo2f(dA[t].y), a2); a3 = fmaf(v, hi2f(dA[t].y), a3);
      a4 = fmaf(v, lo2f(dA[t].z), a4); a5 = fmaf(v, hi2f(dA[t].z), a5);
      a6 = fmaf(v, lo2f(dA[t].w), a6); a7 = fmaf(v, hi2f(dA[t].w), a7);
    }
  }

  if (SUB) {
    u32 s0 = (u32)sv0, s1 = (u32)(sv0 >> 32);
    u32 s2 = (u32)sv1, s3 = (u32)(sv1 >> 32);
    a0 = fmaf(2.f, a0, -lo2f(s0)); a1 = fmaf(2.f, a1, -hi2f(s0));
    a2 = fmaf(2.f, a2, -lo2f(s1)); a3 = fmaf(2.f, a3, -hi2f(s1));
    a4 = fmaf(2.f, a4, -lo2f(s2)); a5 = fmaf(2.f, a5, -hi2f(s2));
    a6 = fmaf(2.f, a6, -lo2f(s3)); a7 = fmaf(2.f, a7, -hi2f(s3));
  }
  u64 rv0 = ((u64)(((u32)f2bf(a3) << 16) | (u32)f2bf(a2)) << 32) |
            (u64)(((u32)f2bf(a1) << 16) | (u32)f2bf(a0));
  u64 rv1 = ((u64)(((u32)f2bf(a7) << 16) | (u32)f2bf(a6)) << 32) |
            (u64)(((u32)f2bf(a5) << 16) | (u32)f2bf(a4));
  char* yp = y + (size_t)s * SLICEB + (size_t)rid * 64 + qb;
  __builtin_nontemporal_store(rv0, (u64*)yp);
  __builtin_nontemporal_store(rv1, (u64*)(yp + 8));
}

// ---------------- Final contraction via MFMA ----------------
// out[(b*M+m)*32+o] = sum_{k,f} xs_k[m][b*16+f] * kern[(f*5+k)*32+o] + bias[o]
// kk = c*32 + g*8 + j <-> k = 2c+(g>>1), f = (g&1)*8+j; 3 chunks of K=32.
// B-frags use ADJACENT output cols per lane (o = 2*col, 2*col+1) -> float2
// stores. pair = blockIdx&7 -> block reading slice p runs on XCD p.

__global__ __launch_bounds__(256) void cheb_gemm_mfma(const char* __restrict__ xs0,
                                                      const float* __restrict__ kern,
                                                      const float* __restrict__ bias,
                                                      float* __restrict__ out) {
  __shared__ unsigned short bl[3][4][32][8];  // [c][g][o][j] = B_kk,o  (6 KB)
  __shared__ float bsl[32];
  int tid = threadIdx.x;
  for (int idx = tid; idx < 3 * 4 * 32 * 8; idx += 256) {
    int j = idx & 7, o = (idx >> 3) & 31, g = (idx >> 8) & 3, c = idx >> 10;
    int k = 2 * c + (g >> 1), f = (g & 1) * 8 + j;
    bl[c][g][o][j] = (k < K) ? f2bf(kern[(f * K + k) * F1 + o]) : (unsigned short)0;
  }
  if (tid < 32) bsl[tid] = bias[tid];
  __syncthreads();

  int lane = tid & 63, wave = tid >> 6;
  int pair = blockIdx.x & 7;
  int bb = wave & 1;
  int mtg = (blockIdx.x >> 3) * 2 + (wave >> 1);   // 0..383
  int b = pair * 2 + bb;
  int mt0 = mtg * 8;                               // first 16-row m-tile of 8

  int row = lane & 15, g = lane >> 4;
  int col = lane & 15;

  s16x8 bf[3][2];
#pragma unroll
  for (int c = 0; c < 3; ++c) {
#pragma unroll
    for (int ot = 0; ot < 2; ++ot)
      bf[c][ot] = *(const s16x8*)(&bl[c][g][2 * col + ot][0]);
  }
  float bias0 = bsl[2 * col], bias1 = bsl[2 * col + 1];

  size_t lanebyte = (size_t)pair * SLICEB + (size_t)row * 64 +
                    (size_t)bb * 32 + (size_t)(g & 1) * 16;
  int khalf = g >> 1;
  const char* p0 = xs0 + (size_t)(0 + khalf) * BUFBYTES + lanebyte;
  const char* p1 = xs0 + (size_t)(2 + khalf) * BUFBYTES + lanebyte;
  const char* p2 = xs0 + (size_t)(4 + khalf) * BUFBYTES + lanebyte;  // valid g<2

  size_t obase0 = ((size_t)b * M + (size_t)mt0 * 16) * F1;

#pragma unroll 2
  for (int t = 0; t < 8; ++t) {
    size_t moff = (size_t)(mt0 + t) * (16 * 64);
    s16x8 a0 = *(const s16x8*)(p0 + moff);
    s16x8 a1 = *(const s16x8*)(p1 + moff);
    s16x8 a2 = (g < 2) ? *(const s16x8*)(p2 + moff) : (s16x8)0;

    f32x4 acc0 = {0.f, 0.f, 0.f, 0.f};
    f32x4 acc1 = {0.f, 0.f, 0.f, 0.f};
    acc0 = __builtin_amdgcn_mfma_f32_16x16x32_bf16(a0, bf[0][0], acc0, 0, 0, 0);
    acc1 = __builtin_amdgcn_mfma_f32_16x16x32_bf16(a0, bf[0][1], acc1, 0, 0, 0);
    acc0 = __builtin_amdgcn_mfma_f32_16x16x32_bf16(a1, bf[1][0], acc0, 0, 0, 0);
    acc1 = __builtin_amdgcn_mfma_f32_16x16x32_bf16(a1, bf[1][1], acc1, 0, 0, 0);
    acc0 = __builtin_amdgcn_mfma_f32_16x16x32_bf16(a2, bf[2][0], acc0, 0, 0, 0);
    acc1 = __builtin_amdgcn_mfma_f32_16x16x32_bf16(a2, bf[2][1], acc1, 0, 0, 0);

    float* ob = out + obase0 + (size_t)t * (16 * F1);
#pragma unroll
    for (int j = 0; j < 4; ++j) {
      int r = g * 4 + j;
      float2 st = make_float2(acc0[j] + bias0, acc1[j] + bias1);
      *(float2*)(ob + r * F1 + 2 * col) = st;
    }
  }
}

// ---------------- launch ----------------

extern "C" void kernel_launch(void* const* d_in, const int* in_sizes, int n_in,
                              void* d_out, int out_size, void* d_ws, size_t ws_size,
                              hipStream_t stream) {
  const float* x    = (const float*)d_in[0];
  const int*   rows = (const int*)d_in[1];
  const int*   cols = (const int*)d_in[2];
  const float* vals = (const float*)d_in[3];
  const float* kern = (const float*)d_in[4];
  const float* bias = (const float*)d_in[5];
  float* out = (float*)d_out;
  int nnz = in_sizes[1];
  int padWords = nnz + 8 * M + 256;               // cvp8 upper bound

  // workspace layout (~130 MiB); xs buffers contiguous, each slice-major.
  char* x0b = (char*)d_ws;
  char* x1b = x0b + BUFBYTES;
  char* x2b = x1b + BUFBYTES;
  char* x3b = x2b + BUFBYTES;
  char* x4b = x3b + BUFBYTES;
  int* row_ptr8 = (int*)(x4b + BUFBYTES);         // M+1 (padded to M+256)
  int* counts   = row_ptr8 + (M + 256);           // M  (raw degree)
  int* fill     = counts + M;                     // M  (scatter cursor)
  int* c8       = fill + M;                       // M  (padded counts)
  int* partials = c8 + M;                         // 64 (padded to 256)
  int* blkhist  = partials + 256;                 // 12288 bin-major hist
  int* sc       = blkhist + NHB;                  // 12288+1 (padded to +256)
  int* perm     = sc + NHB + 256;                 // M
  u32* cvp8     = (u32*)(perm + M);               // padded cv words

  int nblk1024 = M / 1024;                        // 48
  int nblkH    = NHB / 1024;                      // 12
  int nblkNnz  = (nnz + 255) / 256;

  transform_x<<<(M / 16) * 4, 256, 0, stream>>>(x, x0b);

  hipMemsetAsync(counts, 0, (size_t)2 * M * 4, stream);   // counts + fill
  hipMemsetAsync(cvp8, 0, (size_t)padWords * 4, stream);  // pad words = 0
  hist_kernel<<<nblkNnz, 256, 0, stream>>>(rows, counts, nnz);
  // c8 + degree histogram in one pass
  deg_hist_blk<<<NBLK_M, 256, 0, stream>>>(counts, c8, blkhist);
  // row_ptr8 = exclusive scan of padded counts
  scan_blocks<<<nblk1024, 1024, 0, stream>>>(c8, row_ptr8, partials);
  scan_partials_kernel<<<1, 64, 0, stream>>>(partials, row_ptr8, nblk1024);
  scan_add_kernel<<<nblk1024, 1024, 0, stream>>>(row_ptr8, partials);
  // counting-sort offsets
  scan_blocks<<<nblkH, 1024, 0, stream>>>(blkhist, sc, partials);
  scan_partials_kernel<<<1, 64, 0, stream>>>(partials, sc, nblkH);
  scan_add_kernel<<<nblkH, 1024, 0, stream>>>(sc, partials);
  perm_scatter_blk<<<NBLK_M, 256, 0, stream>>>(counts, sc, perm);
  // CSR scatter into padded layout
  scatter_kernel<<<nblkNnz, 256, 0, stream>>>(rows, cols, vals, row_ptr8, fill, cvp8, nnz);

  // Chebyshev recurrence (bf16, slice-major, fp32 accumulate)
  int spmmGrid = 8 * (M / 64);                    // 6144 blocks
  spmm_pad16<false><<<spmmGrid, 256, 0, stream>>>(x0b, nullptr, x1b, row_ptr8, perm, cvp8);
  spmm_pad16<true ><<<spmmGrid, 256, 0, stream>>>(x1b, x0b, x2b, row_ptr8, perm, cvp8);
  spmm_pad16<true ><<<spmmGrid, 256, 0, stream>>>(x2b, x1b, x3b, row_ptr8, perm, cvp8);
  spmm_pad16<true ><<<spmmGrid, 256, 0, stream>>>(x3b, x2b, x4b, row_ptr8, perm, cvp8);

  // final contraction + bias via MFMA: 1536 blocks x 4 waves
  cheb_gemm_mfma<<<1536, 256, 0, stream>>>(x0b, kern, bias, out);

  (void)n_in; (void)out_size; (void)ws_size; (void)in_sizes;
}

// Round 12
// 261.359 us; speedup vs baseline: 1.1624x; 1.0825x over previous
//
#include <hip/hip_runtime.h>

// GraphConvolution (Chebyshev K=5) on MI355X — round 12.
// vs round 11:
//  (a) gemm FUSED into spmm pass 4: x4 computed in regs -> bf16 LDS tile ->
//      MFMA contraction immediately; x4 never touches global memory
//      (-24 MB write, -24 MB read, -1 launch). Pass 4 runs in identity row
//      order (no perm) so A-frag reads (x0..x3 rows) and out stores are
//      contiguous; passes 1-3 keep the degree-sorted perm.
//  (b) the two exclusive-scan chains merged into ONE scan over the 61440-entry
//      concat [c8 | blkhist]: row_ptr8 = D[0..M], perm offset = D[M+i]-D[M].
//      18 -> 14 dispatches.
// Unchanged: [8][M][32] bf16 slice layout (slice = blockIdx&7 -> XCD),
// padded-CSR branch-free strips, 16-B gathers, counting sort for passes 1-3.

constexpr int M   = 49152;
constexpr int B   = 16;
constexpr int FIN = 16;
constexpr int F1  = 32;
constexpr int K   = 5;
constexpr int XBS = M * FIN;                 // per-b stride in x[B,M,FIN]
constexpr size_t SLICEB   = (size_t)M * 64;  // bytes per feature slice
constexpr size_t BUFBYTES = (size_t)M * 512; // bytes per xs_k buffer (8 slices)
constexpr int NBLK_M = M / 256;              // 192 blocks over rows
constexpr int NHB = 64 * NBLK_M;             // 12288 bin-major hist entries
constexpr int NCAT = M + NHB;                // 61440 = 60*1024

typedef short s16x8 __attribute__((ext_vector_type(8)));
typedef float f32x4 __attribute__((ext_vector_type(4)));
typedef unsigned int u32;
typedef unsigned long long u64;
typedef u32 u32x4 __attribute__((ext_vector_type(4)));

#define DEVFN __device__ __forceinline__

DEVFN float lo2f(u32 d) {
  union { u32 u; float f; } v; v.u = d << 16; return v.f;
}
DEVFN float hi2f(u32 d) {
  union { u32 u; float f; } v; v.u = d & 0xffff0000u; return v.f;
}
DEVFN unsigned short f2bf(float f) {   // round-to-nearest-even
  union { float f; u32 u; } v;
  v.f = f;
  u32 r = (v.u + 0x7FFFu + ((v.u >> 16) & 1u)) >> 16;
  return (unsigned short)r;
}
DEVFN u32 pack2(float lo, float hi) {
  return ((u32)f2bf(hi) << 16) | (u32)f2bf(lo);
}

// ---------------- x -> bf16 slice-major [8][M][32], coalesced ----------------

__global__ __launch_bounds__(256) void transform_x(const float* __restrict__ x,
                                                   char* __restrict__ x0b) {
  int lane = threadIdx.x & 63, wave = threadIdx.x >> 6;
  int mchunk = blockIdx.x >> 2, bquad = blockIdx.x & 3;
  int b = bquad * 4 + wave;
  int m = mchunk * 16 + (lane >> 2);
  int f = (lane & 3) * 4;
  float4 v = *(const float4*)(x + (size_t)b * XBS + (size_t)m * FIN + f);
  ushort4 r = make_ushort4(f2bf(v.x), f2bf(v.y), f2bf(v.z), f2bf(v.w));
  *(ushort4*)(x0b + (size_t)(b >> 1) * SLICEB + (size_t)m * 64 +
              (size_t)(b & 1) * 32 + (size_t)(lane & 3) * 8) = r;
}

// ---------------- CSR build ----------------

__global__ __launch_bounds__(256) void hist_kernel(const int* __restrict__ rows,
                                                   int* __restrict__ counts, int nnz) {
  int i = blockIdx.x * 256 + threadIdx.x;
  if (i < nnz) atomicAdd(&counts[rows[i]], 1);
}

DEVFN int wave_incl_scan(int v, int lane) {
#pragma unroll
  for (int off = 1; off < 64; off <<= 1) {
    int t = __shfl_up(v, off);
    if (lane >= off) v += t;
  }
  return v;
}

// per-block inclusive scan of src -> dst[i+1], block total -> partials
__global__ __launch_bounds__(1024) void scan_blocks(const int* __restrict__ src,
                                                    int* __restrict__ dst,
                                                    int* __restrict__ partials) {
  __shared__ int wsum[16];
  int tid = threadIdx.x, lane = tid & 63, w = tid >> 6;
  int i = blockIdx.x * 1024 + tid;
  int s = wave_incl_scan(src[i], lane);
  if (lane == 63) wsum[w] = s;
  __syncthreads();
  if (tid < 16) {
    int t = wsum[tid];
#pragma unroll
    for (int off = 1; off < 16; off <<= 1) {
      int u = __shfl_up(t, off);
      if (tid >= off) t += u;
    }
    wsum[tid] = t;
  }
  __syncthreads();
  int base = (w > 0) ? wsum[w - 1] : 0;
  s += base;
  dst[i + 1] = s;
  if (tid == 1023) partials[blockIdx.x] = s;
}

__global__ void scan_partials_kernel(int* __restrict__ partials,
                                     int* __restrict__ dst, int nblk) {
  int lane = threadIdx.x;  // 64 threads
  int v = (lane < nblk) ? partials[lane] : 0;
  v = wave_incl_scan(v, lane);
  if (lane < nblk) partials[lane] = v;
  if (lane == 0) dst[0] = 0;
}

__global__ __launch_bounds__(1024) void scan_add_kernel(int* __restrict__ dst,
                                                        const int* __restrict__ partials) {
  if (blockIdx.x == 0) return;
  int i = blockIdx.x * 1024 + threadIdx.x;
  dst[i + 1] += partials[blockIdx.x - 1];
}

// cv entry: col (high 16) | val-bf16 (low 16); scattered into the PADDED
// layout (bases from row_ptr8 = D; pad gaps stay 0 from the memset)
__global__ __launch_bounds__(256) void scatter_kernel(const int* __restrict__ rows,
                                                      const int* __restrict__ cols,
                                                      const float* __restrict__ vals,
                                                      const int* __restrict__ row_ptr8,
                                                      int* __restrict__ fill,
                                                      u32* __restrict__ cvp, int nnz) {
  int i = blockIdx.x * 256 + threadIdx.x;
  if (i < nnz) {
    int r = rows[i];
    int pos = row_ptr8[r] + atomicAdd(&fill[r], 1);
    cvp[pos] = ((u32)cols[i] << 16) | (u32)f2bf(vals[i]);
  }
}

// ---------------- degree counting sort (contention-free) ----------------
// emits into the concat array cc: cc[m] = padded counts (strict next multiple
// of 8, >= deg+1); cc[M + bin*192 + blk] = per-block degree histogram.

__global__ __launch_bounds__(256) void deg_hist_blk(const int* __restrict__ counts,
                                                    int* __restrict__ cc) {
  __shared__ int lh[64];
  int tid = threadIdx.x;
  if (tid < 64) lh[tid] = 0;
  __syncthreads();
  int m = blockIdx.x * 256 + tid;
  int d = counts[m];
  cc[m] = (d + 8) & ~7;
  atomicAdd(&lh[min(d, 63)], 1);
  __syncthreads();
  if (tid < 64) cc[M + tid * NBLK_M + blockIdx.x] = lh[tid];
}

__global__ __launch_bounds__(256) void perm_scatter_blk(const int* __restrict__ counts,
                                                        const int* __restrict__ sc,
                                                        int* __restrict__ perm) {
  __shared__ int lh[64];
  __shared__ int lbase[64];
  int tid = threadIdx.x, blk = blockIdx.x;
  if (tid < 64) lh[tid] = 0;
  __syncthreads();
  int m = blk * 256 + tid;
  int d = min(counts[m], 63);
  int lr = atomicAdd(&lh[d], 1);          // LDS-local rank
  int sc0 = sc[0];                        // = D[M] (broadcast)
  __syncthreads();
  if (tid < 64) lbase[tid] = sc[tid * NBLK_M + blk] - sc0;
  __syncthreads();
  perm[lbase[d] + lr] = m;
}

// ---------------- SpMM passes 1-3: sliced, padded-CSR, 16-B gathers --------

template <bool SUB>
__global__ __launch_bounds__(256) void spmm_pad16(const char* __restrict__ xsrc,
                                                  const char* __restrict__ ssrc,
                                                  char* __restrict__ y,
                                                  const int* __restrict__ row_ptr8,
                                                  const int* __restrict__ perm,
                                                  const u32* __restrict__ cvp) {
  int s  = blockIdx.x & 7;
  int g4 = blockIdx.x >> 3;
  int lane = threadIdx.x & 63, wave = threadIdx.x >> 6;
  int r = lane >> 2, q2 = lane & 3;
  int grp = g4 * 4 + wave;                 // 16-row group index
  const char* sbase = xsrc + (size_t)s * SLICEB;
  size_t qb = (size_t)q2 * 16;

  int rid  = perm[grp * 16 + r];
  int base = row_ptr8[rid];
  int plim = row_ptr8[rid + 1] - base - 1;   // last word: always pad (=0)

  int wns = (plim + 1) >> 3;
  wns = max(wns, __shfl_xor(wns, 4));
  wns = max(wns, __shfl_xor(wns, 8));
  wns = max(wns, __shfl_xor(wns, 16));
  wns = max(wns, __shfl_xor(wns, 32));

  u64 sv0 = 0, sv1 = 0;
  if (SUB) {
    const char* sp = ssrc + (size_t)s * SLICEB + (size_t)rid * 64 + qb;
    sv0 = __builtin_nontemporal_load((const u64*)sp);
    sv1 = __builtin_nontemporal_load((const u64*)(sp + 8));
  }

  float a0 = 0.f, a1 = 0.f, a2 = 0.f, a3 = 0.f;
  float a4 = 0.f, a5 = 0.f, a6 = 0.f, a7 = 0.f;
  int nedge = wns * 8;
  for (int t0 = 0; t0 < nedge; t0 += 8) {
    u32 cA[8];
    u32x4 dA[8];
#pragma unroll
    for (int t = 0; t < 8; ++t) cA[t] = cvp[base + min(t0 + t, plim)];
#pragma unroll
    for (int t = 0; t < 8; ++t)
      dA[t] = *(const u32x4*)(sbase + (size_t)(cA[t] >> 16) * 64 + qb);
#pragma unroll
    for (int t = 0; t < 8; ++t) {
      float v = lo2f(cA[t]);
      a0 = fmaf(v, lo2f(dA[t].x), a0); a1 = fmaf(v, hi2f(dA[t].x), a1);
      a2 = fmaf(v, lo2f(dA[t].y), a2); a3 = fmaf(v, hi2f(dA[t].y), a3);
      a4 = fmaf(v, lo2f(dA[t].z), a4); a5 = fmaf(v, hi2f(dA[t].z), a5);
      a6 = fmaf(v, lo2f(dA[t].w), a6); a7 = fmaf(v, hi2f(dA[t].w), a7);
    }
  }

  if (SUB) {
    u32 s0 = (u32)sv0, s1 = (u32)(sv0 >> 32);
    u32 s2 = (u32)sv1, s3 = (u32)(sv1 >> 32);
    a0 = fmaf(2.f, a0, -lo2f(s0)); a1 = fmaf(2.f, a1, -hi2f(s0));
    a2 = fmaf(2.f, a2, -lo2f(s1)); a3 = fmaf(2.f, a3, -hi2f(s1));
    a4 = fmaf(2.f, a4, -lo2f(s2)); a5 = fmaf(2.f, a5, -hi2f(s2));
    a6 = fmaf(2.f, a6, -lo2f(s3)); a7 = fmaf(2.f, a7, -hi2f(s3));
  }
  u64 rv0 = ((u64)pack2(a2, a3) << 32) | (u64)pack2(a0, a1);
  u64 rv1 = ((u64)pack2(a6, a7) << 32) | (u64)pack2(a4, a5);
  char* yp = y + (size_t)s * SLICEB + (size_t)rid * 64 + qb;
  __builtin_nontemporal_store(rv0, (u64*)yp);
  __builtin_nontemporal_store(rv1, (u64*)(yp + 8));
}

// ---------------- Fused pass 4 + gemm ----------------
// Block = slice s (XCD s) x 64 rows (identity order), 4 waves x 16 rows.
// Phase A: x4 = 2 L x3 - x2 in regs (same strip loop) -> bf16 LDS tile.
// Phase C: out[b=2s+bb, rows, :] via MFMA; A chunks c=0,1 from x0..x3 global
// (contiguous rows), c=2 from the LDS x4 tile (g>=2 lanes zero).
// B-table kk = c*32+g*8+j <-> k=2c+(g>>1), f=(g&1)*8+j; o = 2*col+ot.

__global__ __launch_bounds__(256) void spmm_gemm_fused(const char* __restrict__ xsrc,
                                                       const char* __restrict__ ssrc,
                                                       const char* __restrict__ xs0,
                                                       const float* __restrict__ kern,
                                                       const float* __restrict__ bias,
                                                       const int* __restrict__ row_ptr8,
                                                       const u32* __restrict__ cvp,
                                                       float* __restrict__ out) {
  __shared__ unsigned short bl[3][4][32][8];  // 6 KB
  __shared__ float bsl[32];
  __shared__ u32 x4t[4][16][16];              // [wave][row][16 u32] = 4 KB
  int tid = threadIdx.x;
  for (int idx = tid; idx < 3 * 4 * 32 * 8; idx += 256) {
    int j = idx & 7, o = (idx >> 3) & 31, g = (idx >> 8) & 3, c = idx >> 10;
    int k = 2 * c + (g >> 1), f = (g & 1) * 8 + j;
    bl[c][g][o][j] = (k < K) ? f2bf(kern[(f * K + k) * F1 + o]) : (unsigned short)0;
  }
  if (tid < 32) bsl[tid] = bias[tid];

  int s  = blockIdx.x & 7;
  int rg = blockIdx.x >> 3;
  int lane = tid & 63, wave = tid >> 6;
  int m0w = rg * 64 + wave * 16;

  // ---- phase A: spmm for rows m0w..m0w+15 (identity order)
  {
    int r = lane >> 2, q2 = lane & 3;
    int rid = m0w + r;
    const char* sbase = xsrc + (size_t)s * SLICEB;
    size_t qb = (size_t)q2 * 16;
    int base = row_ptr8[rid];
    int plim = row_ptr8[rid + 1] - base - 1;
    int wns = (plim + 1) >> 3;
    wns = max(wns, __shfl_xor(wns, 4));
    wns = max(wns, __shfl_xor(wns, 8));
    wns = max(wns, __shfl_xor(wns, 16));
    wns = max(wns, __shfl_xor(wns, 32));

    const char* sp = ssrc + (size_t)s * SLICEB + (size_t)rid * 64 + qb;
    u64 sv0 = __builtin_nontemporal_load((const u64*)sp);
    u64 sv1 = __builtin_nontemporal_load((const u64*)(sp + 8));

    float a0 = 0.f, a1 = 0.f, a2 = 0.f, a3 = 0.f;
    float a4 = 0.f, a5 = 0.f, a6 = 0.f, a7 = 0.f;
    int nedge = wns * 8;
    for (int t0 = 0; t0 < nedge; t0 += 8) {
      u32 cA[8];
      u32x4 dA[8];
#pragma unroll
      for (int t = 0; t < 8; ++t) cA[t] = cvp[base + min(t0 + t, plim)];
#pragma unroll
      for (int t = 0; t < 8; ++t)
        dA[t] = *(const u32x4*)(sbase + (size_t)(cA[t] >> 16) * 64 + qb);
#pragma unroll
      for (int t = 0; t < 8; ++t) {
        float v = lo2f(cA[t]);
        a0 = fmaf(v, lo2f(dA[t].x), a0); a1 = fmaf(v, hi2f(dA[t].x), a1);
        a2 = fmaf(v, lo2f(dA[t].y), a2); a3 = fmaf(v, hi2f(dA[t].y), a3);
        a4 = fmaf(v, lo2f(dA[t].z), a4); a5 = fmaf(v, hi2f(dA[t].z), a5);
        a6 = fmaf(v, lo2f(dA[t].w), a6); a7 = fmaf(v, hi2f(dA[t].w), a7);
      }
    }
    u32 s0 = (u32)sv0, s1 = (u32)(sv0 >> 32);
    u32 s2 = (u32)sv1, s3 = (u32)(sv1 >> 32);
    a0 = fmaf(2.f, a0, -lo2f(s0)); a1 = fmaf(2.f, a1, -hi2f(s0));
    a2 = fmaf(2.f, a2, -lo2f(s1)); a3 = fmaf(2.f, a3, -hi2f(s1));
    a4 = fmaf(2.f, a4, -lo2f(s2)); a5 = fmaf(2.f, a5, -hi2f(s2));
    a6 = fmaf(2.f, a6, -lo2f(s3)); a7 = fmaf(2.f, a7, -hi2f(s3));

    x4t[wave][r][q2 * 4 + 0] = pack2(a0, a1);
    x4t[wave][r][q2 * 4 + 1] = pack2(a2, a3);
    x4t[wave][r][q2 * 4 + 2] = pack2(a4, a5);
    x4t[wave][r][q2 * 4 + 3] = pack2(a6, a7);
  }
  __syncthreads();

  // ---- phase C: gemm for b = 2s, 2s+1
  int row = lane & 15, g = lane >> 4;
  int col = row;

  s16x8 bf_[3][2];
#pragma unroll
  for (int c = 0; c < 3; ++c) {
#pragma unroll
    for (int ot = 0; ot < 2; ++ot)
      bf_[c][ot] = *(const s16x8*)(&bl[c][g][2 * col + ot][0]);
  }
  float bias0 = bsl[2 * col], bias1 = bsl[2 * col + 1];

  size_t rowbyte = (size_t)s * SLICEB + (size_t)(m0w + row) * 64 +
                   (size_t)(g & 1) * 16;
  int khalf = g >> 1;
  const char* pc0 = xs0 + (size_t)khalf * BUFBYTES + rowbyte;        // k=0/1
  const char* pc1 = xs0 + (size_t)(2 + khalf) * BUFBYTES + rowbyte;  // k=2/3

#pragma unroll
  for (int bb = 0; bb < 2; ++bb) {
    s16x8 A0 = *(const s16x8*)(pc0 + bb * 32);
    s16x8 A1 = *(const s16x8*)(pc1 + bb * 32);
    s16x8 A2 = (g < 2) ? *(const s16x8*)(&x4t[wave][row][bb * 8 + (g & 1) * 4])
                       : (s16x8)0;

    f32x4 acc0 = {0.f, 0.f, 0.f, 0.f};
    f32x4 acc1 = {0.f, 0.f, 0.f, 0.f};
    acc0 = __builtin_amdgcn_mfma_f32_16x16x32_bf16(A0, bf_[0][0], acc0, 0, 0, 0);
    acc1 = __builtin_amdgcn_mfma_f32_16x16x32_bf16(A0, bf_[0][1], acc1, 0, 0, 0);
    acc0 = __builtin_amdgcn_mfma_f32_16x16x32_bf16(A1, bf_[1][0], acc0, 0, 0, 0);
    acc1 = __builtin_amdgcn_mfma_f32_16x16x32_bf16(A1, bf_[1][1], acc1, 0, 0, 0);
    acc0 = __builtin_amdgcn_mfma_f32_16x16x32_bf16(A2, bf_[2][0], acc0, 0, 0, 0);
    acc1 = __builtin_amdgcn_mfma_f32_16x16x32_bf16(A2, bf_[2][1], acc1, 0, 0, 0);

    size_t ob = ((size_t)(2 * s + bb) * M + m0w) * F1;
#pragma unroll
    for (int j = 0; j < 4; ++j) {
      int crow = g * 4 + j;
      float2 st = make_float2(acc0[j] + bias0, acc1[j] + bias1);
      *(float2*)(out + ob + (size_t)crow * F1 + 2 * col) = st;
    }
  }
}

// ---------------- launch ----------------

extern "C" void kernel_launch(void* const* d_in, const int* in_sizes, int n_in,
                              void* d_out, int out_size, void* d_ws, size_t ws_size,
                              hipStream_t stream) {
  const float* x    = (const float*)d_in[0];
  const int*   rows = (const int*)d_in[1];
  const int*   cols = (const int*)d_in[2];
  const float* vals = (const float*)d_in[3];
  const float* kern = (const float*)d_in[4];
  const float* bias = (const float*)d_in[5];
  float* out = (float*)d_out;
  int nnz = in_sizes[1];
  int padWords = nnz + 8 * M + 256;               // cvp8 upper bound

  // workspace layout (~105 MiB); x0b..x3b contiguous, each slice-major.
  char* x0b = (char*)d_ws;
  char* x1b = x0b + BUFBYTES;
  char* x2b = x1b + BUFBYTES;
  char* x3b = x2b + BUFBYTES;
  int* counts   = (int*)(x3b + BUFBYTES);         // M  (raw degree)
  int* fill     = counts + M;                     // M  (scatter cursor)
  int* cc       = fill + M;                       // NCAT concat [c8 | blkhist]
  int* D        = cc + NCAT;                      // NCAT+1 scanned (pad 256)
  int* partials = D + NCAT + 256;                 // 64 (padded to 256)
  int* perm     = partials + 256;                 // M
  u32* cvp8     = (u32*)(perm + M);               // padded cv words
  int* sc       = D + M;                          // perm offsets view

  int nblkCat = NCAT / 1024;                      // 60
  int nblkNnz = (nnz + 255) / 256;

  transform_x<<<(M / 16) * 4, 256, 0, stream>>>(x, x0b);

  hipMemsetAsync(counts, 0, (size_t)2 * M * 4, stream);   // counts + fill
  hipMemsetAsync(cvp8, 0, (size_t)padWords * 4, stream);  // pad words = 0
  hist_kernel<<<nblkNnz, 256, 0, stream>>>(rows, counts, nnz);
  // padded counts + degree histogram into cc (one pass)
  deg_hist_blk<<<NBLK_M, 256, 0, stream>>>(counts, cc);
  // single scan over concat: D[0..M] = row_ptr8, D[M..] = perm offsets (+D[M])
  scan_blocks<<<nblkCat, 1024, 0, stream>>>(cc, D, partials);
  scan_partials_kernel<<<1, 64, 0, stream>>>(partials, D, nblkCat);
  scan_add_kernel<<<nblkCat, 1024, 0, stream>>>(D, partials);
  perm_scatter_blk<<<NBLK_M, 256, 0, stream>>>(counts, sc, perm);
  scatter_kernel<<<nblkNnz, 256, 0, stream>>>(rows, cols, vals, D, fill, cvp8, nnz);

  // Chebyshev recurrence (bf16, slice-major, fp32 accumulate)
  int spmmGrid = 8 * (M / 64);                    // 6144 blocks
  spmm_pad16<false><<<spmmGrid, 256, 0, stream>>>(x0b, nullptr, x1b, D, perm, cvp8);
  spmm_pad16<true ><<<spmmGrid, 256, 0, stream>>>(x1b, x0b, x2b, D, perm, cvp8);
  spmm_pad16<true ><<<spmmGrid, 256, 0, stream>>>(x2b, x1b, x3b, D, perm, cvp8);

  // fused pass 4 + contraction (x4 never hits memory)
  spmm_gemm_fused<<<spmmGrid, 256, 0, stream>>>(x3b, x2b, x0b, kern, bias, D,
                                                cvp8, out);

  (void)n_in; (void)out_size; (void)ws_size; (void)in_sizes;
}